// Round 6
// baseline (105.287 us; speedup 1.0000x reference)
//
#include <hip/hip_runtime.h>
#include <math.h>

// ChamferDistanceL1: B=8, N=M=4096, fp32.
// R12: occupancy-first fused kernel. R11 post-mortem: LDS-atomic y-combine
// fixed R10's disaster (fused ~35us, out of top-5) but missed the 15-20us
// target. R8's 89.6% VALUBusy came with VGPR 24 + 4 blocks/CU (32 waves);
// R11 had QPT=16 (~90 VGPR) + 2 blocks/CU (16 waves) -> ~50% occupancy
// ceiling. R12: QPT=8/LPG=8 (R10's VGPR-52 shape), launch_bounds(512,8)
// (forces <=64 VGPR, 8 waves/SIMD), y split in 2 halves -> 1024 blocks =
// 4 blocks/CU = one full 8-wave/SIMD pass. Two dispatches, zero global
// atomics in the hot loop: fused stores x-partials (256KB) + y-tables
// (8MB) into the unconditionally-poison-filled d_ws; reduce kernel
// min-combines + sums + 128 atomicAdds (out zeroed by fused block 0).
// Predict fused 13-17us, reduce ~3us, total ~65-72us (fill ~42.5 stays).

#define BLK 512
#define QPB 64        // x-queries per block
#define LPG 8         // lanes per group
#define NGRP (BLK / LPG)        // 64 groups
#define QPT (QPB / LPG)         // 8 queries per thread
#define SLICE 1024    // y-points staged in LDS per slice
#define GRANGE (SLICE / NGRP)   // 16 y-points per group per slice
#define NWAVE (BLK / 64)        // 8
#define NXT 64        // x-tiles per batch (4096 / QPB)
#define YHALF 2048    // y-points per block (z-split)

#define YPART_FLOATS (8 * NXT * 2 * YHALF)  // 2,097,152 floats = 8 MB

__global__ void zero_out_kernel(float* __restrict__ out) { out[0] = 0.0f; }

// ---- fused kernel (N == M == 4096) ----
__global__ __launch_bounds__(BLK, 8) void chamfer_fused_kernel(
    const float* __restrict__ x, const float* __restrict__ y,
    float* __restrict__ out, unsigned* __restrict__ wsY,
    float* __restrict__ wsX) {
  __shared__ float4 sdb[NGRP][GRANGE + 1];   // 64*17*16 B = 17.4 KB
  __shared__ unsigned ymin[YHALF];           // 8 KB block-local y mins
  __shared__ float pmin[NWAVE][QPB];         // 2 KB

  const int b = blockIdx.y;
  const int xblk = blockIdx.x;
  const int half = blockIdx.z;
  const float* __restrict__ qb  = x + (size_t)b * 4096 * 3;
  const float* __restrict__ dbb = y + ((size_t)b * 4096 + half * YHALF) * 3;

  const int t = threadIdx.x;
  const int g = t >> 3;  // group id [0,64)
  const int u = t & 7;   // lane-in-group

  if (xblk == 0 && b == 0 && half == 0 && t == 0) out[0] = 0.0f;

  // init block-local ymin table to +FLT_MAX bits
#pragma unroll
  for (int r = 0; r < YHALF / BLK; ++r) ymin[t + r * BLK] = 0x7F7FFFFFu;

  const int q0 = xblk * QPB;
  float qx[QPT], qy[QPT], qz[QPT], dmin[QPT];
#pragma unroll
  for (int k = 0; k < QPT; ++k) {
    const int qi = q0 + u + LPG * k;
    qx[k] = qb[3 * qi + 0];
    qy[k] = qb[3 * qi + 1];
    qz[k] = qb[3 * qi + 2];
    dmin[k] = 3.0e38f;
  }

  for (int s0 = 0; s0 < YHALF; s0 += SLICE) {
    // ---- stage SLICE y-points into LDS ----
#pragma unroll
    for (int r = 0; r < SLICE / BLK; ++r) {
      const int p = t + r * BLK;
      const int j = s0 + p;
      sdb[p >> 4][p & 15] =
          make_float4(dbb[3 * j + 0], dbb[3 * j + 1], dbb[3 * j + 2], 0.0f);
    }
    __syncthreads();

    // ---- this group's GRANGE points vs this lane's 8 queries ----
#pragma unroll
    for (int tt = 0; tt < GRANGE; tt += 2) {
      const float4 p0 = sdb[g][tt];
      const float4 p1 = sdb[g][tt + 1];
      float m0, m1, c0, c1;
      m0 = m1 = c0 = c1 = 3.0e38f;
#pragma unroll
      for (int k = 0; k < QPT; ++k) {
        const float d0 =
            fabsf(qx[k] - p0.x) + fabsf(qy[k] - p0.y) + fabsf(qz[k] - p0.z);
        const float d1 =
            fabsf(qx[k] - p1.x) + fabsf(qy[k] - p1.y) + fabsf(qz[k] - p1.z);
        dmin[k] = fminf(dmin[k], fminf(d0, d1));  // v_min3_f32
        if (k == 0) {
          m0 = d0;
          m1 = d1;
        } else if (k & 1) {
          if (k == 1) {
            m0 = fminf(m0, d0);
            m1 = fminf(m1, d1);
          } else {
            m0 = fminf(m0, fminf(c0, d0));  // v_min3_f32
            m1 = fminf(m1, fminf(c1, d1));  // v_min3_f32
          }
        } else {
          c0 = d0;
          c1 = d1;
        }
      }
      // block-local y-min: 8 lanes/address ds_min_u32 (dist>=0 -> uint
      // order == float order); LDS pipe, overlaps the VALU burst.
      atomicMin(&ymin[s0 + (g << 4) + tt], __float_as_uint(m0));
      atomicMin(&ymin[s0 + (g << 4) + tt + 1], __float_as_uint(m1));
    }
    __syncthreads();
  }

  // ---- dump block-local ymin table to private ws slice (coalesced) ----
  // layout: [b][xblk][half][YHALF]
  unsigned* __restrict__ wyb =
      wsY + (((size_t)b * NXT + xblk) * 2 + half) * YHALF;
#pragma unroll
  for (int r = 0; r < YHALF / BLK; ++r) {
    const int i = t + r * BLK;
    wyb[i] = ymin[i];
  }

  // ---- x-side: combine the 8 groups inside each wave (lane bits 3,4,5) ---
#pragma unroll
  for (int k = 0; k < QPT; ++k) {
    float m = dmin[k];
    m = fminf(m, __shfl_xor(m, 8, 64));
    m = fminf(m, __shfl_xor(m, 16, 64));
    m = fminf(m, __shfl_xor(m, 32, 64));
    dmin[k] = m;
  }
  const int w = t >> 6;
  if ((t & 63) < LPG) {
#pragma unroll
    for (int k = 0; k < QPT; ++k) pmin[w][u + LPG * k] = dmin[k];
  }
  __syncthreads();

  // ---- cross-wave min; plain-store per-query half-min (no atomics) ----
  if (t < QPB) {
    float m = pmin[0][t];
#pragma unroll
    for (int ww = 1; ww < NWAVE; ++ww) m = fminf(m, pmin[ww][t]);
    // layout: [b][half][xblk][QPB]
    wsX[(((size_t)b * 2 + half) * NXT + xblk) * QPB + t] = m;
  }
}

// ---- reduce: y 64-way min + x 2-way min, scaled sum -> 128 atomicAdds ----
__global__ __launch_bounds__(256) void reduce_kernel(
    const unsigned* __restrict__ wsY, const float* __restrict__ wsX,
    float* __restrict__ out, float sx, float sy) {
  const int tid = blockIdx.x * 256 + threadIdx.x;  // [0, 8*4096)
  const int b = tid >> 12;
  const int j = tid & 4095;

  // y-side: min over the 64 x-blocks' partials for y-point (b, j)
  const int h = j >> 11;
  const int jj = j & (YHALF - 1);
  const unsigned* __restrict__ py =
      wsY + (((size_t)b * NXT) * 2 + h) * YHALF + jj;
  unsigned um = 0x7F7FFFFFu;
#pragma unroll 8
  for (int xb = 0; xb < NXT; ++xb) um = min(um, py[(size_t)xb * 2 * YHALF]);

  // x-side: min over the 2 y-halves for query (b, i=j)
  const int xb = j >> 6, qi = j & 63;
  const float v0 = wsX[(((size_t)b * 2 + 0) * NXT + xb) * QPB + qi];
  const float v1 = wsX[(((size_t)b * 2 + 1) * NXT + xb) * QPB + qi];

  float s = __uint_as_float(um) * sy + fminf(v0, v1) * sx;
#pragma unroll
  for (int o = 32; o > 0; o >>= 1) s += __shfl_down(s, o, 64);
  __shared__ float ws[4];
  const int w = threadIdx.x >> 6;
  if ((threadIdx.x & 63) == 0) ws[w] = s;
  __syncthreads();
  if (threadIdx.x == 0) atomicAdd(out, ws[0] + ws[1] + ws[2] + ws[3]);
}

// ---------------- generic fallback (any N, M): R8 two-dir kernel ----------
#define GBLK 512
#define GQPB 64
#define GQPT 4
#define GSLICE 1024
#define GNGRP 32
#define GGRANGE (GSLICE / GNGRP)

__global__ __launch_bounds__(GBLK) void chamfer_generic_kernel(
    const float* __restrict__ x, const float* __restrict__ y,
    float* __restrict__ out, int N, int M, float sx, float sy) {
  __shared__ float4 sdb[GNGRP][GGRANGE + 1];
  __shared__ float pmin[GBLK / 64][GQPB];
  const int dir = blockIdx.z;
  const int b = blockIdx.y;
  const float* __restrict__ q  = dir ? y : x;
  const float* __restrict__ db = dir ? x : y;
  const int Nq  = dir ? M : N;
  const int Ndb = dir ? N : M;
  const float scale = dir ? sy : sx;
  const float* __restrict__ qb  = q  + (size_t)b * Nq  * 3;
  const float* __restrict__ dbb = db + (size_t)b * Ndb * 3;
  const int t = threadIdx.x;
  const int g = t >> 4, u = t & 15;
  const int q0 = blockIdx.x * GQPB;
  float qx[GQPT], qy[GQPT], qz[GQPT], dmin[GQPT];
#pragma unroll
  for (int k = 0; k < GQPT; ++k) {
    int qi = q0 + u + 16 * k;
    if (qi >= Nq) qi = Nq - 1;
    qx[k] = qb[3 * qi + 0];
    qy[k] = qb[3 * qi + 1];
    qz[k] = qb[3 * qi + 2];
    dmin[k] = 3.0e38f;
  }
  for (int s0 = 0; s0 < Ndb; s0 += GSLICE) {
    const int send = min(GSLICE, Ndb - s0);
    for (int p = t; p < send; p += GBLK) {
      const int j = s0 + p;
      sdb[p >> 5][p & 31] =
          make_float4(dbb[3 * j + 0], dbb[3 * j + 1], dbb[3 * j + 2], 0.0f);
    }
    __syncthreads();
    const int base = g * GGRANGE;
    const int lim = min(GGRANGE, max(0, send - base));
    for (int tt = 0; tt < lim; ++tt) {
      const float4 p0 = sdb[g][tt];
#pragma unroll
      for (int k = 0; k < GQPT; ++k) {
        const float d0 =
            fabsf(qx[k] - p0.x) + fabsf(qy[k] - p0.y) + fabsf(qz[k] - p0.z);
        dmin[k] = fminf(dmin[k], d0);
      }
    }
    __syncthreads();
  }
#pragma unroll
  for (int k = 0; k < GQPT; ++k) {
    float m = dmin[k];
    m = fminf(m, __shfl_xor(m, 16, 64));
    m = fminf(m, __shfl_xor(m, 32, 64));
    dmin[k] = m;
  }
  const int w = t >> 6, l = t & 63;
  if (l < 16) {
#pragma unroll
    for (int k = 0; k < GQPT; ++k) pmin[w][l + 16 * k] = dmin[k];
  }
  __syncthreads();
  if (t < GQPB) {
    float m = pmin[0][t];
#pragma unroll
    for (int ww = 1; ww < GBLK / 64; ++ww) m = fminf(m, pmin[ww][t]);
    if (q0 + t >= Nq) m = 0.0f;
#pragma unroll
    for (int o = 32; o > 0; o >>= 1) m += __shfl_down(m, o, 64);
    if (t == 0) atomicAdd(out, m * scale);
  }
}

extern "C" void kernel_launch(void* const* d_in, const int* in_sizes, int n_in,
                              void* d_out, int out_size, void* d_ws, size_t ws_size,
                              hipStream_t stream) {
  const float* x = (const float*)d_in[0];
  const float* y = (const float*)d_in[1];
  const int B = 8;
  const int N = in_sizes[0] / (B * 3);
  const int M = in_sizes[1] / (B * 3);

  float* out = (float*)d_out;
  unsigned* wsY = (unsigned*)d_ws;                  // 8 MB
  float* wsX = (float*)d_ws + YPART_FLOATS;         // + 256 KB
  const float sx = 1.0f / (float)(B * N);
  const float sy = 1.0f / (float)(B * M);

  const bool fused =
      (N == 4096 && M == 4096 &&
       ws_size >= (size_t)(YPART_FLOATS + 8 * 2 * NXT * QPB) * 4);
  if (fused) {
    dim3 grd(NXT, B, 2);  // 64 x-tiles * 8 batches * 2 y-halves = 1024
    chamfer_fused_kernel<<<grd, dim3(BLK), 0, stream>>>(x, y, out, wsY, wsX);
    reduce_kernel<<<(8 * 4096) / 256, 256, 0, stream>>>(wsY, wsX, out, sx, sy);
  } else {
    zero_out_kernel<<<1, 1, 0, stream>>>(out);
    const int mx = (N > M) ? N : M;
    dim3 grd((mx + GQPB - 1) / GQPB, B, 2);
    chamfer_generic_kernel<<<grd, dim3(GBLK), 0, stream>>>(
        x, y, out, N, M, sx, sy);
  }
}

// Round 7
// 82.281 us; speedup vs baseline: 1.2796x; 1.2796x over previous
//
#include <hip/hip_runtime.h>
#include <math.h>

// ChamferDistanceL1: B=8, N=M=4096, fp32.
// R13: rotation kernel -- both chamfer reductions lane-local.
// R12 post-mortem: SQ_LDS_BANK_CONFLICT=7.86M proved same-address
// ds_min_u32 (8 lanes/addr) serializes ~30 cyc/atomic; VALUBusy 36%.
// Every attempt so far (shuffles R9, global atomics R10, LDS atomics
// R11/R12) paid a PER-PAIR cross-lane combine. R13 restructures:
//  - lane owns 8 FIXED y-points in regs for the whole kernel (block =
//    64-x-tile x all 4096 y); y-min = 8 private regs, flushed once by
//    plain coalesced store. Zero per-pair y combining.
//  - x-queries in LDS SoA; ROTATION: step s, lane t handles x=(t+2s)&63
//    and (t+2s+1)&63 -> every ds_min_u32 instruction hits 64 DISTINCT
//    dword entries (2 lanes/bank = free). 64 atomics/lane TOTAL.
//  - block x-mins are final (full y coverage); reduce kernel 64-way-mins
//    the y tables (8MB) + sums both sides -> 128 atomicAdds.
// Floor ~12us; predict fused 14-18us, conflicts <0.5M, VALUBusy >=80%,
// total ~70us (42.5us unconditional ws poison-fill stays).

#define BLK 512
#define QPB 64        // x-queries per block
#define NXT 64        // x-tiles per batch
#define YPT 8         // y-points per thread (512*8 = 4096)
#define NWAVE 8

#define WSY_DWORDS (8 * NXT * 4096)  // 2,097,152 dwords = 8 MB

__global__ void zero_out_kernel(float* __restrict__ out) { out[0] = 0.0f; }

// ---- fused kernel (N == M == 4096) ----
__global__ __launch_bounds__(BLK, 4) void chamfer_fused_kernel(
    const float* __restrict__ x, const float* __restrict__ y,
    float* __restrict__ out, unsigned* __restrict__ wsY,
    float* __restrict__ wsX) {
  __shared__ float xsx[QPB];
  __shared__ float xsy[QPB];
  __shared__ float xsz[QPB];
  __shared__ unsigned xmin[QPB];

  const int b = blockIdx.y;
  const int xblk = blockIdx.x;
  const float* __restrict__ qb  = x + (size_t)b * 4096 * 3;
  const float* __restrict__ dbb = y + (size_t)b * 4096 * 3;
  const int t = threadIdx.x;

  if (b == 0 && xblk == 0 && t == 0) out[0] = 0.0f;  // reduce runs after us

  // stage the 64 x-queries (SoA) + init x-min table
  if (t < QPB) {
    const int qi = xblk * QPB + t;
    xsx[t] = qb[3 * qi + 0];
    xsy[t] = qb[3 * qi + 1];
    xsz[t] = qb[3 * qi + 2];
    xmin[t] = 0x7F7FFFFFu;
  }

  // this lane's 8 fixed y-points (coalesced: j = r*512 + t)
  float pyx[YPT], pyy[YPT], pyz[YPT], yacc[YPT];
#pragma unroll
  for (int r = 0; r < YPT; ++r) {
    const int j = r * BLK + t;
    pyx[r] = dbb[3 * j + 0];
    pyy[r] = dbb[3 * j + 1];
    pyz[r] = dbb[3 * j + 2];
    yacc[r] = 3.0e38f;
  }
  __syncthreads();

  // ---- rotation over the 64 x-queries, 2 per step ----
#pragma unroll 4
  for (int s = 0; s < 32; ++s) {
    const int xa = (t + 2 * s) & 63;
    const int xb = (xa + 1) & 63;
    const float ax = xsx[xa], ay = xsy[xa], az = xsz[xa];
    const float bx = xsx[xb], by = xsy[xb], bz = xsz[xb];
    float da[YPT], db[YPT];
#pragma unroll
    for (int r = 0; r < YPT; ++r) {
      da[r] = fabsf(ax - pyx[r]) + fabsf(ay - pyy[r]) + fabsf(az - pyz[r]);
      db[r] = fabsf(bx - pyx[r]) + fabsf(by - pyy[r]) + fabsf(bz - pyz[r]);
      yacc[r] = fminf(yacc[r], fminf(da[r], db[r]));  // v_min3_f32
    }
    // x-side: min over this lane's 8 y (4-op min3 trees), then one
    // distinct-entry LDS atomic per x (lanes hit 64 different dwords).
    const float a012 = fminf(fminf(da[0], da[1]), da[2]);
    const float a345 = fminf(fminf(da[3], da[4]), da[5]);
    const float a67  = fminf(fminf(da[6], da[7]), a012);
    const float ma = fminf(a345, a67);
    const float b012 = fminf(fminf(db[0], db[1]), db[2]);
    const float b345 = fminf(fminf(db[3], db[4]), db[5]);
    const float b67  = fminf(fminf(db[6], db[7]), b012);
    const float mb = fminf(b345, b67);
    atomicMin(&xmin[xa], __float_as_uint(ma));
    atomicMin(&xmin[xb], __float_as_uint(mb));
  }
  __syncthreads();

  // ---- flush: y partials (plain coalesced), x finals ----
  unsigned* __restrict__ wyb = wsY + ((size_t)b * NXT + xblk) * 4096;
#pragma unroll
  for (int r = 0; r < YPT; ++r) {
    wyb[r * BLK + t] = __float_as_uint(yacc[r]);
  }
  if (t < QPB) {
    wsX[((size_t)b * NXT + xblk) * QPB + t] = __uint_as_float(xmin[t]);
  }
}

// ---- reduce: y 64-way min (+sy), x final sum (+sx) -> 128 atomicAdds ----
__global__ __launch_bounds__(256) void reduce_kernel(
    const unsigned* __restrict__ wsY, const float* __restrict__ wsX,
    float* __restrict__ out, float sx, float sy) {
  const int tid = blockIdx.x * 256 + threadIdx.x;  // [0, 32768)
  const int b = tid >> 12;
  const int j = tid & 4095;

  // y-side: min over the 64 x-blocks' partials for y-point (b, j)
  const unsigned* __restrict__ py = wsY + ((size_t)b * NXT) * 4096 + j;
  unsigned um = 0x7F7FFFFFu;
#pragma unroll 8
  for (int xb = 0; xb < NXT; ++xb) um = min(um, py[(size_t)xb * 4096]);

  // x-side: entry tid is already a final x-min
  float s = __uint_as_float(um) * sy + wsX[tid] * sx;
#pragma unroll
  for (int o = 32; o > 0; o >>= 1) s += __shfl_down(s, o, 64);
  __shared__ float ws[4];
  const int w = threadIdx.x >> 6;
  if ((threadIdx.x & 63) == 0) ws[w] = s;
  __syncthreads();
  if (threadIdx.x == 0) atomicAdd(out, ws[0] + ws[1] + ws[2] + ws[3]);
}

// ---------------- generic fallback (any N, M): R8 two-dir kernel ----------
#define GBLK 512
#define GQPB 64
#define GQPT 4
#define GSLICE 1024
#define GNGRP 32
#define GGRANGE (GSLICE / GNGRP)

__global__ __launch_bounds__(GBLK) void chamfer_generic_kernel(
    const float* __restrict__ x, const float* __restrict__ y,
    float* __restrict__ out, int N, int M, float sx, float sy) {
  __shared__ float4 sdb[GNGRP][GGRANGE + 1];
  __shared__ float pmin[GBLK / 64][GQPB];
  const int dir = blockIdx.z;
  const int b = blockIdx.y;
  const float* __restrict__ q  = dir ? y : x;
  const float* __restrict__ db = dir ? x : y;
  const int Nq  = dir ? M : N;
  const int Ndb = dir ? N : M;
  const float scale = dir ? sy : sx;
  const float* __restrict__ qb  = q  + (size_t)b * Nq  * 3;
  const float* __restrict__ dbb = db + (size_t)b * Ndb * 3;
  const int t = threadIdx.x;
  const int g = t >> 4, u = t & 15;
  const int q0 = blockIdx.x * GQPB;
  float qx[GQPT], qy[GQPT], qz[GQPT], dmin[GQPT];
#pragma unroll
  for (int k = 0; k < GQPT; ++k) {
    int qi = q0 + u + 16 * k;
    if (qi >= Nq) qi = Nq - 1;
    qx[k] = qb[3 * qi + 0];
    qy[k] = qb[3 * qi + 1];
    qz[k] = qb[3 * qi + 2];
    dmin[k] = 3.0e38f;
  }
  for (int s0 = 0; s0 < Ndb; s0 += GSLICE) {
    const int send = min(GSLICE, Ndb - s0);
    for (int p = t; p < send; p += GBLK) {
      const int j = s0 + p;
      sdb[p >> 5][p & 31] =
          make_float4(dbb[3 * j + 0], dbb[3 * j + 1], dbb[3 * j + 2], 0.0f);
    }
    __syncthreads();
    const int base = g * GGRANGE;
    const int lim = min(GGRANGE, max(0, send - base));
    for (int tt = 0; tt < lim; ++tt) {
      const float4 p0 = sdb[g][tt];
#pragma unroll
      for (int k = 0; k < GQPT; ++k) {
        const float d0 =
            fabsf(qx[k] - p0.x) + fabsf(qy[k] - p0.y) + fabsf(qz[k] - p0.z);
        dmin[k] = fminf(dmin[k], d0);
      }
    }
    __syncthreads();
  }
#pragma unroll
  for (int k = 0; k < GQPT; ++k) {
    float m = dmin[k];
    m = fminf(m, __shfl_xor(m, 16, 64));
    m = fminf(m, __shfl_xor(m, 32, 64));
    dmin[k] = m;
  }
  const int w = t >> 6, l = t & 63;
  if (l < 16) {
#pragma unroll
    for (int k = 0; k < GQPT; ++k) pmin[w][l + 16 * k] = dmin[k];
  }
  __syncthreads();
  if (t < GQPB) {
    float m = pmin[0][t];
#pragma unroll
    for (int ww = 1; ww < GBLK / 64; ++ww) m = fminf(m, pmin[ww][t]);
    if (q0 + t >= Nq) m = 0.0f;
#pragma unroll
    for (int o = 32; o > 0; o >>= 1) m += __shfl_down(m, o, 64);
    if (t == 0) atomicAdd(out, m * scale);
  }
}

extern "C" void kernel_launch(void* const* d_in, const int* in_sizes, int n_in,
                              void* d_out, int out_size, void* d_ws, size_t ws_size,
                              hipStream_t stream) {
  const float* x = (const float*)d_in[0];
  const float* y = (const float*)d_in[1];
  const int B = 8;
  const int N = in_sizes[0] / (B * 3);
  const int M = in_sizes[1] / (B * 3);

  float* out = (float*)d_out;
  unsigned* wsY = (unsigned*)d_ws;                 // 8 MB
  float* wsX = (float*)d_ws + WSY_DWORDS;          // + 128 KB
  const float sx = 1.0f / (float)(B * N);
  const float sy = 1.0f / (float)(B * M);

  const bool fused =
      (N == 4096 && M == 4096 &&
       ws_size >= (size_t)(WSY_DWORDS + 8 * NXT * QPB) * 4);
  if (fused) {
    dim3 grd(NXT, B);  // 64 x-tiles * 8 batches = 512 blocks
    chamfer_fused_kernel<<<grd, dim3(BLK), 0, stream>>>(x, y, out, wsY, wsX);
    reduce_kernel<<<(8 * 4096) / 256, 256, 0, stream>>>(wsY, wsX, out, sx, sy);
  } else {
    zero_out_kernel<<<1, 1, 0, stream>>>(out);
    const int mx = (N > M) ? N : M;
    dim3 grd((mx + GQPB - 1) / GQPB, B, 2);
    chamfer_generic_kernel<<<grd, dim3(GBLK), 0, stream>>>(
        x, y, out, N, M, sx, sy);
  }
}

// Round 8
// 81.371 us; speedup vs baseline: 1.2939x; 1.0112x over previous
//
#include <hip/hip_runtime.h>
#include <math.h>

// ChamferDistanceL1: B=8, N=M=4096, fp32.
// R14: R13 rotation + occupancy fix. R13 (82.3us total, best) was capped at
// 4 waves/SIMD: pairs/lane=512 (64-x window x YPT=8) -> 4096 waves total =
// 50% occupancy, with LDS pipe ~90% as loaded as VALU (6 ds_read_b32 + 2
// ds-atomic per 16 pairs) -> latency not hidden (R12 measured the same
// symptom: VALUBusy 36%). R14:
//  - YPT=4 + y split in halves -> 1024 blocks = 4/CU = 8 waves/SIMD (full),
//    launch_bounds(512,8) to cap VGPR at 64.
//  - x tables replicated to 128 entries: xs[xa], xs[xa+1] read without wrap
//    mask -> ds_read2_b32 merge (3 LDS reads/step instead of 6).
//  - zero_out kernel dropped on fused path (fused block 0 zeroes out).
// Rate model: VALU 0.30 pair/cyc/CU vs LDS 0.27 -> fused ~16us. Predict
// total 82.3 -> 66-71 (fill ~42 unconditional, reduce ~4, gaps ~5).

#define BLK 512
#define QPB 64        // x-queries per block
#define NXT 64        // x-tiles per batch
#define YPT 4         // y-points per thread (512*4 = 2048 = half)
#define YHALF 2048

#define WSY_DWORDS (8 * NXT * 2 * YHALF)  // 2,097,152 dwords = 8 MB
#define WSX_DWORDS (8 * 2 * NXT * QPB)    // 65,536 dwords = 256 KB

__global__ void zero_out_kernel(float* __restrict__ out) { out[0] = 0.0f; }

// ---- fused kernel (N == M == 4096) ----
__global__ __launch_bounds__(BLK, 8) void chamfer_fused_kernel(
    const float* __restrict__ x, const float* __restrict__ y,
    float* __restrict__ out, unsigned* __restrict__ wsY,
    float* __restrict__ wsX) {
  __shared__ float xsx[2 * QPB];   // replicated: [q] and [q+64] hold same
  __shared__ float xsy[2 * QPB];
  __shared__ float xsz[2 * QPB];
  __shared__ unsigned xmin[QPB];

  const int b = blockIdx.y;
  const int xblk = blockIdx.x;
  const int half = blockIdx.z;
  const float* __restrict__ qb  = x + (size_t)b * 4096 * 3;
  const float* __restrict__ dbb = y + ((size_t)b * 4096 + half * YHALF) * 3;
  const int t = threadIdx.x;

  if (b == 0 && xblk == 0 && half == 0 && t == 0) out[0] = 0.0f;

  // stage 64 x-queries (SoA, replicated x2 for wrap-free adjacent reads)
  if (t < QPB) {
    const int qi = xblk * QPB + t;
    const float vx = qb[3 * qi + 0];
    const float vy = qb[3 * qi + 1];
    const float vz = qb[3 * qi + 2];
    xsx[t] = vx; xsx[t + QPB] = vx;
    xsy[t] = vy; xsy[t + QPB] = vy;
    xsz[t] = vz; xsz[t + QPB] = vz;
    xmin[t] = 0x7F7FFFFFu;
  }

  // this lane's 4 fixed y-points (j = r*512 + t within the half)
  float pyx[YPT], pyy[YPT], pyz[YPT], yacc[YPT];
#pragma unroll
  for (int r = 0; r < YPT; ++r) {
    const int j = r * BLK + t;
    pyx[r] = dbb[3 * j + 0];
    pyy[r] = dbb[3 * j + 1];
    pyz[r] = dbb[3 * j + 2];
    yacc[r] = 3.0e38f;
  }
  __syncthreads();

  // ---- rotation over the 64 x-queries, 2 per step ----
#pragma unroll 2
  for (int s = 0; s < 32; ++s) {
    const int xa = (t + 2 * s) & 63;
    // adjacent reads from the replica -> ds_read2_b32, no wrap mask
    const float ax = xsx[xa], axn = xsx[xa + 1];
    const float ay = xsy[xa], ayn = xsy[xa + 1];
    const float az = xsz[xa], azn = xsz[xa + 1];
    float d0[YPT], d1[YPT];
#pragma unroll
    for (int r = 0; r < YPT; ++r) {
      d0[r] = fabsf(ax - pyx[r]) + fabsf(ay - pyy[r]) + fabsf(az - pyz[r]);
      d1[r] = fabsf(axn - pyx[r]) + fabsf(ayn - pyy[r]) + fabsf(azn - pyz[r]);
      yacc[r] = fminf(yacc[r], fminf(d0[r], d1[r]));  // v_min3_f32
    }
    const float ma = fminf(fminf(d0[0], d0[1]), fminf(d0[2], d0[3]));
    const float mb = fminf(fminf(d1[0], d1[1]), fminf(d1[2], d1[3]));
    // distinct-address within each wave instruction (xa distinct per lane)
    atomicMin(&xmin[xa], __float_as_uint(ma));
    atomicMin(&xmin[(xa + 1) & 63], __float_as_uint(mb));
  }
  __syncthreads();

  // ---- flush: y partials (coalesced), x half-finals ----
  unsigned* __restrict__ wyb =
      wsY + (((size_t)b * NXT + xblk) * 2 + half) * YHALF;
#pragma unroll
  for (int r = 0; r < YPT; ++r) {
    wyb[r * BLK + t] = __float_as_uint(yacc[r]);
  }
  if (t < QPB) {
    wsX[(((size_t)b * 2 + half) * NXT + xblk) * QPB + t] =
        __uint_as_float(xmin[t]);
  }
}

// ---- reduce: y 64-way min (+sy), x 2-way min (+sx) -> 128 atomicAdds ----
__global__ __launch_bounds__(256) void reduce_kernel(
    const unsigned* __restrict__ wsY, const float* __restrict__ wsX,
    float* __restrict__ out, float sx, float sy) {
  const int tid = blockIdx.x * 256 + threadIdx.x;  // [0, 32768)
  const int b = tid >> 12;
  const int j = tid & 4095;

  // y-side: min over the 64 x-blocks' partials for y-point (b, j)
  const int h = j >> 11;
  const int jj = j & (YHALF - 1);
  const unsigned* __restrict__ py =
      wsY + (((size_t)b * NXT) * 2 + h) * YHALF + jj;
  unsigned um = 0x7F7FFFFFu;
#pragma unroll 8
  for (int xb = 0; xb < NXT; ++xb) um = min(um, py[(size_t)xb * 2 * YHALF]);

  // x-side: min over the 2 y-halves for query (b, i=j)
  const int xt = j >> 6, q = j & 63;
  const float v0 = wsX[(((size_t)b * 2 + 0) * NXT + xt) * QPB + q];
  const float v1 = wsX[(((size_t)b * 2 + 1) * NXT + xt) * QPB + q];

  float s = __uint_as_float(um) * sy + fminf(v0, v1) * sx;
#pragma unroll
  for (int o = 32; o > 0; o >>= 1) s += __shfl_down(s, o, 64);
  __shared__ float ws[4];
  const int w = threadIdx.x >> 6;
  if ((threadIdx.x & 63) == 0) ws[w] = s;
  __syncthreads();
  if (threadIdx.x == 0) atomicAdd(out, ws[0] + ws[1] + ws[2] + ws[3]);
}

// ---------------- generic fallback (any N, M): R8 two-dir kernel ----------
#define GBLK 512
#define GQPB 64
#define GQPT 4
#define GSLICE 1024
#define GNGRP 32
#define GGRANGE (GSLICE / GNGRP)

__global__ __launch_bounds__(GBLK) void chamfer_generic_kernel(
    const float* __restrict__ x, const float* __restrict__ y,
    float* __restrict__ out, int N, int M, float sx, float sy) {
  __shared__ float4 sdb[GNGRP][GGRANGE + 1];
  __shared__ float pmin[GBLK / 64][GQPB];
  const int dir = blockIdx.z;
  const int b = blockIdx.y;
  const float* __restrict__ q  = dir ? y : x;
  const float* __restrict__ db = dir ? x : y;
  const int Nq  = dir ? M : N;
  const int Ndb = dir ? N : M;
  const float scale = dir ? sy : sx;
  const float* __restrict__ qb  = q  + (size_t)b * Nq  * 3;
  const float* __restrict__ dbb = db + (size_t)b * Ndb * 3;
  const int t = threadIdx.x;
  const int g = t >> 4, u = t & 15;
  const int q0 = blockIdx.x * GQPB;
  float qx[GQPT], qy[GQPT], qz[GQPT], dmin[GQPT];
#pragma unroll
  for (int k = 0; k < GQPT; ++k) {
    int qi = q0 + u + 16 * k;
    if (qi >= Nq) qi = Nq - 1;
    qx[k] = qb[3 * qi + 0];
    qy[k] = qb[3 * qi + 1];
    qz[k] = qb[3 * qi + 2];
    dmin[k] = 3.0e38f;
  }
  for (int s0 = 0; s0 < Ndb; s0 += GSLICE) {
    const int send = min(GSLICE, Ndb - s0);
    for (int p = t; p < send; p += GBLK) {
      const int j = s0 + p;
      sdb[p >> 5][p & 31] =
          make_float4(dbb[3 * j + 0], dbb[3 * j + 1], dbb[3 * j + 2], 0.0f);
    }
    __syncthreads();
    const int base = g * GGRANGE;
    const int lim = min(GGRANGE, max(0, send - base));
    for (int tt = 0; tt < lim; ++tt) {
      const float4 p0 = sdb[g][tt];
#pragma unroll
      for (int k = 0; k < GQPT; ++k) {
        const float d0 =
            fabsf(qx[k] - p0.x) + fabsf(qy[k] - p0.y) + fabsf(qz[k] - p0.z);
        dmin[k] = fminf(dmin[k], d0);
      }
    }
    __syncthreads();
  }
#pragma unroll
  for (int k = 0; k < GQPT; ++k) {
    float m = dmin[k];
    m = fminf(m, __shfl_xor(m, 16, 64));
    m = fminf(m, __shfl_xor(m, 32, 64));
    dmin[k] = m;
  }
  const int w = t >> 6, l = t & 63;
  if (l < 16) {
#pragma unroll
    for (int k = 0; k < GQPT; ++k) pmin[w][l + 16 * k] = dmin[k];
  }
  __syncthreads();
  if (t < GQPB) {
    float m = pmin[0][t];
#pragma unroll
    for (int ww = 1; ww < GBLK / 64; ++ww) m = fminf(m, pmin[ww][t]);
    if (q0 + t >= Nq) m = 0.0f;
#pragma unroll
    for (int o = 32; o > 0; o >>= 1) m += __shfl_down(m, o, 64);
    if (t == 0) atomicAdd(out, m * scale);
  }
}

extern "C" void kernel_launch(void* const* d_in, const int* in_sizes, int n_in,
                              void* d_out, int out_size, void* d_ws, size_t ws_size,
                              hipStream_t stream) {
  const float* x = (const float*)d_in[0];
  const float* y = (const float*)d_in[1];
  const int B = 8;
  const int N = in_sizes[0] / (B * 3);
  const int M = in_sizes[1] / (B * 3);

  float* out = (float*)d_out;
  unsigned* wsY = (unsigned*)d_ws;                 // 8 MB
  float* wsX = (float*)d_ws + WSY_DWORDS;          // + 256 KB
  const float sx = 1.0f / (float)(B * N);
  const float sy = 1.0f / (float)(B * M);

  const bool fused =
      (N == 4096 && M == 4096 &&
       ws_size >= (size_t)(WSY_DWORDS + WSX_DWORDS) * 4);
  if (fused) {
    dim3 grd(NXT, B, 2);  // 64 x-tiles * 8 batches * 2 y-halves = 1024
    chamfer_fused_kernel<<<grd, dim3(BLK), 0, stream>>>(x, y, out, wsY, wsX);
    reduce_kernel<<<(8 * 4096) / 256, 256, 0, stream>>>(wsY, wsX, out, sx, sy);
  } else {
    zero_out_kernel<<<1, 1, 0, stream>>>(out);
    const int mx = (N > M) ? N : M;
    dim3 grd((mx + GQPB - 1) / GQPB, B, 2);
    chamfer_generic_kernel<<<grd, dim3(GBLK), 0, stream>>>(
        x, y, out, N, M, sx, sy);
  }
}